// Round 5
// baseline (505.303 us; speedup 1.0000x reference)
//
#include <hip/hip_runtime.h>
#include <hip/hip_bf16.h>

typedef __attribute__((ext_vector_type(4))) float fx4;
typedef __attribute__((ext_vector_type(8))) short bv8;
typedef unsigned int u32;
typedef unsigned short u16;
typedef __hip_bfloat16 bf16;

#define DEVI static __device__ __forceinline__

static constexpr int NBATCH = 8;
static constexpr int SEQ = 1024;
static constexpr int DM  = 1024;
static constexpr int NH  = 16;
static constexpr int MROWS = NBATCH * SEQ;           // 8192
static constexpr size_t SZ = (size_t)MROWS * DM;     // 8388608

DEVI void gl16(const void* g, void* l) {
  __builtin_amdgcn_global_load_lds((const __attribute__((address_space(1))) void*)g,
                                   (__attribute__((address_space(3))) void*)l, 16, 0, 0);
}
DEVI fx4 mfma_bf16(bv8 a, bv8 b, fx4 c) {
  return __builtin_amdgcn_mfma_f32_16x16x32_bf16(a, b, c, 0, 0, 0);
}

// ---------------- weight prep ----------------
// fc_q/fc_k: 3-term bf16 split (hi+mid+lo) laid out K-CONCATENATED: We[col][s*1024+k].
// A@(B0+B1+B2)^T == [A|A|A] @ concat_K(...)^T -> plain K=3072 GEMM, 32KB LDS.
// fc_v/fc_o: single bf16.
__global__ __launch_bounds__(256) void prep_weights(
    const float* __restrict__ wq, const float* __restrict__ wk,
    const float* __restrict__ wv, const float* __restrict__ wo,
    bf16* __restrict__ qe, bf16* __restrict__ ke,
    bf16* __restrict__ vb, bf16* __restrict__ ob)
{
  int i = (blockIdx.x * 256 + threadIdx.x) * 4;
  int w = blockIdx.y;
  const float* src = (w == 0) ? wq : (w == 1) ? wk : (w == 2) ? wv : wo;
  fx4 v = *(const fx4*)&src[i];
  if (w < 2) {
    bf16* dst = (w == 0) ? qe : ke;
    int col = i >> 10, k = i & 1023;
    size_t base = (size_t)col * 3072 + k;
    bf16 hi[4], mi[4], lo[4];
#pragma unroll
    for (int j = 0; j < 4; j++) {
      float x = v[j];
      bf16 h = __float2bfloat16(x);
      float r1 = x - __bfloat162float(h);
      bf16 m = __float2bfloat16(r1);
      float r2 = r1 - __bfloat162float(m);
      hi[j] = h; mi[j] = m; lo[j] = __float2bfloat16(r2);
    }
    *(uint2*)&dst[base]        = *(const uint2*)hi;
    *(uint2*)&dst[base + 1024] = *(const uint2*)mi;
    *(uint2*)&dst[base + 2048] = *(const uint2*)lo;
  } else {
    bf16* dst = (w == 2) ? vb : ob;
    bf16 t[4];
#pragma unroll
    for (int j = 0; j < 4; j++) t[j] = __float2bfloat16(v[j]);
    *(uint2*)&dst[i] = *(const uint2*)t;
  }
}

// ---------------- LIF spike: (x >= 2) ? 1 : 0, bf16 out ----------------
__global__ __launch_bounds__(256) void spike_kernel(const float* __restrict__ x, u16* __restrict__ o)
{
  size_t i = ((size_t)blockIdx.x * 256 + threadIdx.x) * 4;
  fx4 v = *(const fx4*)&x[i];
  u32 a = (v[0] >= 2.f ? 0x3F80u : 0u) | ((v[1] >= 2.f ? 0x3F80u : 0u) << 16);
  u32 b = (v[2] >= 2.f ? 0x3F80u : 0u) | ((v[3] >= 2.f ? 0x3F80u : 0u) << 16);
  u32* p = (u32*)(o + i);
  p[0] = a; p[1] = b;
}

// ---------------- mask bit-pack, TRANSPOSED: [B,Sq,Skv] f32 -> [B][Skv/32][Sq] u32 ----------------
__global__ __launch_bounds__(256) void maskpack_kernel(const float* __restrict__ m, u32* __restrict__ w)
{
  size_t gid = (size_t)blockIdx.x * 256 + threadIdx.x;
  unsigned long long bal = __ballot(m[gid] != 0.0f);
  int lane = threadIdx.x & 63;
  u32 skv = (u32)(gid & 1023);
  u32 sq  = (u32)((gid >> 10) & 1023);
  u32 b   = (u32)(gid >> 20);
  size_t oidx = (size_t)b * 32768 + (skv >> 5) * 1024 + sq;
  if (lane == 0) w[oidx] = (u32)bal;
  else if (lane == 32) w[oidx] = (u32)(bal >> 32);
}

// ---------------- GEMM: C[M,N] = A[M,(K mod 1024)] @ B[N,K]^T ----------------
// A has leading dim 1024 and is re-read cyclically for K>1024 (K-concatenated weights).
// EPI 0: Cf = acc + bias (f32)
// EPI 2: Cf = addsrc + mish(acc + bias)
// EPI 3: Cb = bf16(acc + bias), stored TRANSPOSED per batch: Cb[b][col][token]
template<int EPI>
__global__ __launch_bounds__(256) void gemm_bt(
    const bf16* __restrict__ A, const bf16* __restrict__ B,
    const float* __restrict__ bias, const float* __restrict__ addsrc,
    float* __restrict__ Cf, bf16* __restrict__ Cb, int K, int N)
{
  __shared__ __attribute__((aligned(16))) bf16 sA[128 * 64];
  __shared__ __attribute__((aligned(16))) bf16 sB[128 * 64];
  const int tid = threadIdx.x;
  const int lane = tid & 63, wave = tid >> 6;
  const int wr = wave >> 1, wc = wave & 1;
  const int l15 = lane & 15, l4 = lane >> 4;
  const int rowBase = blockIdx.x * 128;
  const int colBase = blockIdx.y * 128;

  fx4 acc[4][4];
#pragma unroll
  for (int m = 0; m < 4; m++) {
#pragma unroll
    for (int n = 0; n < 4; n++) acc[m][n] = fx4{0.f, 0.f, 0.f, 0.f};
  }

  for (int kt = 0; kt < K; kt += 64) {
    const int ka = kt & 1023;  // A column (cyclic for K-concatenated weights)
#pragma unroll
    for (int i = 0; i < 4; i++) {
      int c = i * 256 + tid;
      int r = c >> 3, cb = (c & 7) * 8;
      gl16(A + (size_t)(rowBase + r) * 1024 + ka + cb, &sA[c * 8]);
    }
#pragma unroll
    for (int i = 0; i < 4; i++) {
      int c = i * 256 + tid;
      int r = c >> 3, cb = (c & 7) * 8;
      gl16(B + (size_t)(colBase + r) * K + kt + cb, &sB[c * 8]);
    }
    __syncthreads();
#pragma unroll
    for (int kk = 0; kk < 2; kk++) {
      bv8 af[4];
#pragma unroll
      for (int m = 0; m < 4; m++)
        af[m] = *(const bv8*)&sA[(wr * 64 + m * 16 + l15) * 64 + kk * 32 + l4 * 8];
#pragma unroll
      for (int n = 0; n < 4; n++) {
        bv8 bfr = *(const bv8*)&sB[(wc * 64 + n * 16 + l15) * 64 + kk * 32 + l4 * 8];
#pragma unroll
        for (int m = 0; m < 4; m++) acc[m][n] = mfma_bf16(af[m], bfr, acc[m][n]);
      }
    }
    __syncthreads();
  }
#pragma unroll
  for (int n = 0; n < 4; n++) {
    int col = colBase + wc * 64 + n * 16 + l15;
    float bvv = bias[col];
#pragma unroll
    for (int m = 0; m < 4; m++) {
      int row0 = rowBase + wr * 64 + m * 16 + l4 * 4;
      if (EPI == 3) {
        bf16 t[4];
#pragma unroll
        for (int r = 0; r < 4; r++) t[r] = __float2bfloat16(acc[m][n][r] + bvv);
        size_t idx = (size_t)(row0 >> 10) * SEQ * DM + (size_t)col * SEQ + (row0 & 1023);
        *(uint2*)&Cb[idx] = *(const uint2*)t;
      } else {
#pragma unroll
        for (int r = 0; r < 4; r++) {
          size_t idx = (size_t)(row0 + r) * N + col;
          float val = acc[m][n][r] + bvv;
          if (EPI == 0) {
            Cf[idx] = val;
          } else {
            float u = __expf(val);
            float num = u * (u + 2.0f);          // (1+u)^2 - 1
            float mish = val * num / (num + 2.0f);
            Cf[idx] = addsrc[idx] + mish;
          }
        }
      }
    }
  }
}

// ---------------- LayerNorm (two-pass) + LIF threshold -> bf16 binary ----------------
__global__ __launch_bounds__(256) void lnlif_kernel(
    const float* __restrict__ x, const float* __restrict__ g, const float* __restrict__ be,
    u16* __restrict__ out)
{
  __shared__ float red[4];
  const int row = blockIdx.x;
  const int tid = threadIdx.x;
  fx4 v = *(const fx4*)&x[(size_t)row * DM + tid * 4];
  float s = v[0] + v[1] + v[2] + v[3];
#pragma unroll
  for (int off = 1; off < 64; off <<= 1) s += __shfl_xor(s, off, 64);
  if ((tid & 63) == 0) red[tid >> 6] = s;
  __syncthreads();
  float mean = (red[0] + red[1] + red[2] + red[3]) * (1.0f / 1024.0f);
  __syncthreads();
  float d0 = v[0] - mean, d1 = v[1] - mean, d2 = v[2] - mean, d3 = v[3] - mean;
  float ss = d0 * d0 + d1 * d1 + d2 * d2 + d3 * d3;
#pragma unroll
  for (int off = 1; off < 64; off <<= 1) ss += __shfl_xor(ss, off, 64);
  if ((tid & 63) == 0) red[tid >> 6] = ss;
  __syncthreads();
  float var = (red[0] + red[1] + red[2] + red[3]) * (1.0f / 1024.0f);
  float rstd = rsqrtf(var + 1e-5f);
  const int c = tid * 4;
  fx4 gg = *(const fx4*)&g[c];
  fx4 bb = *(const fx4*)&be[c];
  float y0 = d0 * rstd * gg[0] + bb[0];
  float y1 = d1 * rstd * gg[1] + bb[1];
  float y2 = d2 * rstd * gg[2] + bb[2];
  float y3 = d3 * rstd * gg[3] + bb[3];
  u32 a = (y0 >= 2.f ? 0x3F80u : 0u) | ((y1 >= 2.f ? 0x3F80u : 0u) << 16);
  u32 b = (y2 >= 2.f ? 0x3F80u : 0u) | ((y3 >= 2.f ? 0x3F80u : 0u) << 16);
  u32* p = (u32*)(out + (size_t)row * DM + c);
  p[0] = a; p[1] = b;
}

// ---------------- fused masked attention ----------------
// T2 XOR-swizzled sK/sV/sP (pre-swizzled gl16 source, rule #21), K/V double-buffered,
// ONE raw barrier per kv-tile with explicit vmcnt/lgkmcnt, Q direct global->reg,
// transposed bit-mask (2x uint4 LDS reads/tile), deferred psum reduce, setprio MFMA.
__global__ __launch_bounds__(256) void attn_kernel(
    const bf16* __restrict__ qb, const bf16* __restrict__ kb, const bf16* __restrict__ vt,
    const u32* __restrict__ mwT, float* __restrict__ of, bf16* __restrict__ ob)
{
  __shared__ __attribute__((aligned(16))) bf16 sK[2][64 * 64];
  __shared__ __attribute__((aligned(16))) bf16 sV[2][64 * 64];
  __shared__ __attribute__((aligned(16))) bf16 sP[4][16 * 64];
  __shared__ __attribute__((aligned(16))) u32 sM[2][128];
  const int qt = blockIdx.x, h = blockIdx.y, b = blockIdx.z;
  const int tid = threadIdx.x, lane = tid & 63, wave = tid >> 6;
  const int l15 = lane & 15, l4 = lane >> 4;
  const size_t qrow0 = (size_t)b * SEQ + qt * 64;
  const bf16* kB = kb + (size_t)b * SEQ * DM + h * 64;                    // + kvrow*DM + d
  const bf16* vB = vt + (size_t)b * SEQ * DM + (size_t)(h * 64) * SEQ;   // + d*SEQ + kv
  const u32*  mB = mwT + (size_t)b * 32768 + qt * 64;                    // + w*1024 + row

  auto STAGE = [&](int t, int buf) {
    const int kvb = t * 64;
#pragma unroll
    for (int i = 0; i < 2; i++) {
      int c = i * 256 + tid;
      int row = c >> 3;
      int sb = ((c & 7) * 16) ^ ((row & 7) << 4);   // inverse-swizzled source byte
      gl16(kB + (size_t)(kvb + row) * DM + (sb >> 1), &sK[buf][c * 8]);
      gl16(vB + (size_t)row * SEQ + kvb + (sb >> 1), &sV[buf][c * 8]);
    }
    if (tid < 32) {
      int w = tid >> 4, rg = (tid & 15) * 4;
      uint4 mv = *(const uint4*)&mB[(size_t)(t * 2 + w) * 1024 + rg];
      *(uint4*)&sM[buf][w * 64 + rg] = mv;
    }
  };

  bv8 af[2];
#pragma unroll
  for (int kk = 0; kk < 2; kk++)
    af[kk] = *(const bv8*)&qb[(qrow0 + wave * 16 + l15) * DM + h * 64 + kk * 32 + l4 * 8];

  fx4 acc_o[4];
#pragma unroll
  for (int n = 0; n < 4; n++) acc_o[n] = fx4{0.f, 0.f, 0.f, 0.f};
  float psum[4] = {0.f, 0.f, 0.f, 0.f};

  char* sPw = (char*)sP[wave];
  STAGE(0, 0);

  for (int t = 0; t < 16; t++) {
    const int cur = t & 1;
    asm volatile("s_waitcnt vmcnt(0) lgkmcnt(0)" ::: "memory");
    __builtin_amdgcn_s_barrier();
    if (t < 15) STAGE(t + 1, cur ^ 1);

    const char* sKc = (const char*)sK[cur];
    const char* sVc = (const char*)sV[cur];

    fx4 accs[4];
#pragma unroll
    for (int n = 0; n < 4; n++) accs[n] = fx4{0.f, 0.f, 0.f, 0.f};
    __builtin_amdgcn_s_setprio(1);
#pragma unroll
    for (int kk = 0; kk < 2; kk++) {
#pragma unroll
      for (int n = 0; n < 4; n++) {
        int row = n * 16 + l15;
        bv8 bk8 = *(const bv8*)(sKc + row * 128 + ((kk * 64 + l4 * 16) ^ ((row & 7) << 4)));
        accs[n] = mfma_bf16(af[kk], bk8, accs[n]);
      }
    }
    __builtin_amdgcn_s_setprio(0);

    uint4 m0 = *(const uint4*)&sM[cur][wave * 16 + l4 * 4];
    uint4 m1 = *(const uint4*)&sM[cur][64 + wave * 16 + l4 * 4];
    u32 sh0[4] = {m0.x >> l15, m0.y >> l15, m0.z >> l15, m0.w >> l15};
    u32 sh1[4] = {m1.x >> l15, m1.y >> l15, m1.z >> l15, m1.w >> l15};

#pragma unroll
    for (int n = 0; n < 4; n++) {
#pragma unroll
      for (int r = 0; r < 4; r++) {
        float e = exp2f(accs[n][r] * 0.18033688011112042f);  // exp(acc/8)
        u32 s = (n < 2) ? sh0[r] : sh1[r];
        float p = ((s >> ((n & 1) * 16)) & 1u) ? e : 1.0f;
        psum[r] += p;
        int pr = l4 * 4 + r;
        int cb = (n * 16 + l15) * 2;
        *(bf16*)(sPw + pr * 128 + (cb ^ ((pr & 7) << 4))) = __float2bfloat16(p);
      }
    }

    __builtin_amdgcn_s_setprio(1);
#pragma unroll
    for (int kk = 0; kk < 2; kk++) {
      bv8 pa = *(const bv8*)(sPw + l15 * 128 + ((kk * 64 + l4 * 16) ^ ((l15 & 7) << 4)));
#pragma unroll
      for (int n = 0; n < 4; n++) {
        int row = n * 16 + l15;
        bv8 bv8v = *(const bv8*)(sVc + row * 128 + ((kk * 64 + l4 * 16) ^ ((row & 7) << 4)));
        acc_o[n] = mfma_bf16(pa, bv8v, acc_o[n]);
      }
    }
    __builtin_amdgcn_s_setprio(0);
  }

#pragma unroll
  for (int r = 0; r < 4; r++) {
    float t2 = psum[r];
    t2 += __shfl_xor(t2, 1, 64);
    t2 += __shfl_xor(t2, 2, 64);
    t2 += __shfl_xor(t2, 4, 64);
    t2 += __shfl_xor(t2, 8, 64);
    float inv = 1.0f / t2;
    size_t row = qrow0 + wave * 16 + (l4 << 2) + r;
#pragma unroll
    for (int n = 0; n < 4; n++) {
      size_t idx = row * DM + h * 64 + n * 16 + l15;
      float val = acc_o[n][r] * inv;
      of[idx] = val;
      ob[idx] = __float2bfloat16(val);
    }
  }
}

extern "C" void kernel_launch(void* const* d_in, const int* in_sizes, int n_in,
                              void* d_out, int out_size, void* d_ws, size_t ws_size,
                              hipStream_t stream) {
  (void)in_sizes; (void)n_in; (void)out_size; (void)ws_size;
  const float* Q    = (const float*)d_in[0];
  const float* Kin  = (const float*)d_in[1];
  const float* mask = (const float*)d_in[2];
  const float* Wq   = (const float*)d_in[3];
  const float* bq   = (const float*)d_in[4];
  const float* Wk   = (const float*)d_in[5];
  const float* bk   = (const float*)d_in[6];
  const float* Wv   = (const float*)d_in[7];
  const float* bv   = (const float*)d_in[8];
  const float* Wo   = (const float*)d_in[9];
  const float* bo   = (const float*)d_in[10];
  const float* g_q  = (const float*)d_in[11];
  const float* be_q = (const float*)d_in[12];
  const float* g_k  = (const float*)d_in[13];
  const float* be_k = (const float*)d_in[14];
  float* out = (float*)d_out;

  char* w = (char*)d_ws;
  size_t off = 0;
  auto alloc = [&](size_t bytes) -> char* {
    char* p = w + off;
    off += (bytes + 255) & ~(size_t)255;
    return p;
  };
  bf16* q_spike = (bf16*)alloc(SZ * 2);
  bf16* k_spike = (bf16*)alloc(SZ * 2);
  float* xq     = (float*)alloc(SZ * 4);
  float* xk     = (float*)alloc(SZ * 4);
  bf16* vtb     = (bf16*)alloc(SZ * 2);
  u32* mwords   = (u32*)alloc(SZ / 32 * 4);
  bf16* wqe = (bf16*)alloc((size_t)DM * DM * 3 * 2);
  bf16* wke = (bf16*)alloc((size_t)DM * DM * 3 * 2);
  bf16* wvb = (bf16*)alloc((size_t)DM * DM * 2);
  bf16* wob = (bf16*)alloc((size_t)DM * DM * 2);
  // aliases (lifetimes disjoint):
  bf16* qbn = q_spike;          // q_spike dead after fc_q
  bf16* kbn = k_spike;          // k_spike dead after fc_v
  float* attn_out = xq;         // xq dead after lnlif(q)
  bf16* attn_outb = (bf16*)xk;  // xk dead after lnlif(k)

  prep_weights<<<dim3(DM * DM / 1024, 4), 256, 0, stream>>>(Wq, Wk, Wv, Wo, wqe, wke, wvb, wob);
  spike_kernel<<<SZ / 1024, 256, 0, stream>>>(Q, (u16*)q_spike);
  spike_kernel<<<SZ / 1024, 256, 0, stream>>>(Kin, (u16*)k_spike);
  maskpack_kernel<<<SZ / 256, 256, 0, stream>>>(mask, mwords);

  gemm_bt<0><<<dim3(64, 8), 256, 0, stream>>>(q_spike, wqe, bq, nullptr, xq, nullptr, 3072, DM);
  gemm_bt<0><<<dim3(64, 8), 256, 0, stream>>>(k_spike, wke, bk, nullptr, xk, nullptr, 3072, DM);
  gemm_bt<3><<<dim3(64, 8), 256, 0, stream>>>(k_spike, wvb, bv, nullptr, nullptr, vtb, 1024, DM);

  lnlif_kernel<<<MROWS, 256, 0, stream>>>(xq, g_q, be_q, (u16*)qbn);
  lnlif_kernel<<<MROWS, 256, 0, stream>>>(xk, g_k, be_k, (u16*)kbn);

  attn_kernel<<<dim3(16, NH, NBATCH), 256, 0, stream>>>(qbn, kbn, vtb, mwords, attn_out, attn_outb);

  gemm_bt<2><<<dim3(64, 8), 256, 0, stream>>>(attn_outb, wob, bo, attn_out, out, nullptr, 1024, DM);
}

// Round 7
// 476.252 us; speedup vs baseline: 1.0610x; 1.0610x over previous
//
#include <hip/hip_runtime.h>
#include <hip/hip_bf16.h>

typedef __attribute__((ext_vector_type(4))) float fx4;
typedef __attribute__((ext_vector_type(8))) short bv8;
typedef unsigned int u32;
typedef unsigned short u16;
typedef __hip_bfloat16 bf16;

#define DEVI static __device__ __forceinline__

static constexpr int NBATCH = 8;
static constexpr int SEQ = 1024;
static constexpr int DM  = 1024;
static constexpr int NH  = 16;
static constexpr int MROWS = NBATCH * SEQ;           // 8192
static constexpr size_t SZ = (size_t)MROWS * DM;     // 8388608

DEVI void gl16(const void* g, void* l) {
  __builtin_amdgcn_global_load_lds((const __attribute__((address_space(1))) void*)g,
                                   (__attribute__((address_space(3))) void*)l, 16, 0, 0);
}
DEVI fx4 mfma_bf16(bv8 a, bv8 b, fx4 c) {
  return __builtin_amdgcn_mfma_f32_16x16x32_bf16(a, b, c, 0, 0, 0);
}
DEVI u32 cvt_pk_bf16(float a, float b) {  // lo=bf16(a), hi=bf16(b), RNE
  u32 r;
  asm("v_cvt_pk_bf16_f32 %0, %1, %2" : "=v"(r) : "v"(a), "v"(b));
  return r;
}

// ---------------- weight prep ----------------
// fc_q/fc_k: 3-term bf16 split, K-concatenated We[col][s*1024+k] (K=3072 GEMM).
// fc_v/fc_o: single bf16.
__global__ __launch_bounds__(256) void prep_weights(
    const float* __restrict__ wq, const float* __restrict__ wk,
    const float* __restrict__ wv, const float* __restrict__ wo,
    bf16* __restrict__ qe, bf16* __restrict__ ke,
    bf16* __restrict__ vb, bf16* __restrict__ ob)
{
  int i = (blockIdx.x * 256 + threadIdx.x) * 4;
  int w = blockIdx.y;
  const float* src = (w == 0) ? wq : (w == 1) ? wk : (w == 2) ? wv : wo;
  fx4 v = *(const fx4*)&src[i];
  if (w < 2) {
    bf16* dst = (w == 0) ? qe : ke;
    int col = i >> 10, k = i & 1023;
    size_t base = (size_t)col * 3072 + k;
    bf16 hi[4], mi[4], lo[4];
#pragma unroll
    for (int j = 0; j < 4; j++) {
      float x = v[j];
      bf16 h = __float2bfloat16(x);
      float r1 = x - __bfloat162float(h);
      bf16 m = __float2bfloat16(r1);
      float r2 = r1 - __bfloat162float(m);
      hi[j] = h; mi[j] = m; lo[j] = __float2bfloat16(r2);
    }
    *(uint2*)&dst[base]        = *(const uint2*)hi;
    *(uint2*)&dst[base + 1024] = *(const uint2*)mi;
    *(uint2*)&dst[base + 2048] = *(const uint2*)lo;
  } else {
    bf16* dst = (w == 2) ? vb : ob;
    bf16 t[4];
#pragma unroll
    for (int j = 0; j < 4; j++) t[j] = __float2bfloat16(v[j]);
    *(uint2*)&dst[i] = *(const uint2*)t;
  }
}

// ---------------- LIF spike for Q and K in one launch ----------------
__global__ __launch_bounds__(256) void spike2_kernel(
    const float* __restrict__ xq, const float* __restrict__ xk,
    u16* __restrict__ oq, u16* __restrict__ ok)
{
  const float* x = blockIdx.y ? xk : xq;
  u16* o = blockIdx.y ? ok : oq;
  size_t i = ((size_t)blockIdx.x * 256 + threadIdx.x) * 4;
  fx4 v = *(const fx4*)&x[i];
  u32 a = (v[0] >= 2.f ? 0x3F80u : 0u) | ((v[1] >= 2.f ? 0x3F80u : 0u) << 16);
  u32 b = (v[2] >= 2.f ? 0x3F80u : 0u) | ((v[3] >= 2.f ? 0x3F80u : 0u) << 16);
  u32* p = (u32*)(o + i);
  p[0] = a; p[1] = b;
}

// ---------------- mask bit-pack, TRANSPOSED: [B,Sq,Skv] f32 -> [B][Skv/32][Sq] u32 ----------------
__global__ __launch_bounds__(256) void maskpack_kernel(const float* __restrict__ m, u32* __restrict__ w)
{
  size_t gid = (size_t)blockIdx.x * 256 + threadIdx.x;
  unsigned long long bal = __ballot(m[gid] != 0.0f);
  int lane = threadIdx.x & 63;
  u32 skv = (u32)(gid & 1023);
  u32 sq  = (u32)((gid >> 10) & 1023);
  u32 b   = (u32)(gid >> 20);
  size_t oidx = (size_t)b * 32768 + (skv >> 5) * 1024 + sq;
  if (lane == 0) w[oidx] = (u32)bal;
  else if (lane == 32) w[oidx] = (u32)(bal >> 32);
}

// ---------------- fc_q + fc_k merged: one launch, 1024 blocks (4/CU) ----------------
// C[M,1024] = A[M,k mod 1024] @ B[1024,3072]^T  (A cyclic over K-concat weight)
__global__ __launch_bounds__(256) void gemm_qk(
    const bf16* __restrict__ Aq, const bf16* __restrict__ Ak,
    const bf16* __restrict__ Bq, const bf16* __restrict__ Bk,
    const float* __restrict__ biq, const float* __restrict__ bik,
    float* __restrict__ Cq, float* __restrict__ Ck)
{
  __shared__ __attribute__((aligned(16))) bf16 sA[128 * 64];
  __shared__ __attribute__((aligned(16))) bf16 sB[128 * 64];
  const int z = blockIdx.z;
  const bf16* A = z ? Ak : Aq;
  const bf16* B = z ? Bk : Bq;
  const float* bias = z ? bik : biq;
  float* Cf = z ? Ck : Cq;
  const int tid = threadIdx.x;
  const int lane = tid & 63, wave = tid >> 6;
  const int wr = wave >> 1, wc = wave & 1;
  const int l15 = lane & 15, l4 = lane >> 4;
  const int rowBase = blockIdx.x * 128;
  const int colBase = blockIdx.y * 128;

  fx4 acc[4][4];
#pragma unroll
  for (int m = 0; m < 4; m++)
#pragma unroll
    for (int n = 0; n < 4; n++) acc[m][n] = fx4{0.f, 0.f, 0.f, 0.f};

  for (int kt = 0; kt < 3072; kt += 64) {
    const int ka = kt & 1023;
#pragma unroll
    for (int i = 0; i < 4; i++) {
      int c = i * 256 + tid;
      int r = c >> 3, cb = (c & 7) * 8;
      gl16(A + (size_t)(rowBase + r) * 1024 + ka + cb, &sA[c * 8]);
    }
#pragma unroll
    for (int i = 0; i < 4; i++) {
      int c = i * 256 + tid;
      int r = c >> 3, cb = (c & 7) * 8;
      gl16(B + (size_t)(colBase + r) * 3072 + kt + cb, &sB[c * 8]);
    }
    __syncthreads();
#pragma unroll
    for (int kk = 0; kk < 2; kk++) {
      bv8 af[4];
#pragma unroll
      for (int m = 0; m < 4; m++)
        af[m] = *(const bv8*)&sA[(wr * 64 + m * 16 + l15) * 64 + kk * 32 + l4 * 8];
#pragma unroll
      for (int n = 0; n < 4; n++) {
        bv8 bfr = *(const bv8*)&sB[(wc * 64 + n * 16 + l15) * 64 + kk * 32 + l4 * 8];
#pragma unroll
        for (int m = 0; m < 4; m++) acc[m][n] = mfma_bf16(af[m], bfr, acc[m][n]);
      }
    }
    __syncthreads();
  }
#pragma unroll
  for (int n = 0; n < 4; n++) {
    int col = colBase + wc * 64 + n * 16 + l15;
    float bvv = bias[col];
#pragma unroll
    for (int m = 0; m < 4; m++) {
      int row0 = rowBase + wr * 64 + m * 16 + l4 * 4;
#pragma unroll
      for (int r = 0; r < 4; r++)
        Cf[(size_t)(row0 + r) * DM + col] = acc[m][n][r] + bvv;
    }
  }
}

// ---------------- fc_v with SWAPPED MFMA -> direct V^T store ----------------
// VT[b][wcol][token] = bf16( spk_k @ Wv^T + bv )^T  (32B-coalesced u16 stores)
__global__ __launch_bounds__(256) void gemm_vT(
    const bf16* __restrict__ A, const bf16* __restrict__ B,
    const float* __restrict__ bias, bf16* __restrict__ VT)
{
  __shared__ __attribute__((aligned(16))) bf16 sA[128 * 64];
  __shared__ __attribute__((aligned(16))) bf16 sB[128 * 64];
  const int tid = threadIdx.x;
  const int lane = tid & 63, wave = tid >> 6;
  const int wr = wave >> 1, wc = wave & 1;
  const int l15 = lane & 15, l4 = lane >> 4;
  const int rowBase = blockIdx.x * 128;   // tokens
  const int colBase = blockIdx.y * 128;   // weight cols

  fx4 acc[4][4];
#pragma unroll
  for (int m = 0; m < 4; m++)
#pragma unroll
    for (int n = 0; n < 4; n++) acc[m][n] = fx4{0.f, 0.f, 0.f, 0.f};

  for (int kt = 0; kt < 1024; kt += 64) {
#pragma unroll
    for (int i = 0; i < 4; i++) {
      int c = i * 256 + tid;
      int r = c >> 3, cb = (c & 7) * 8;
      gl16(A + (size_t)(rowBase + r) * 1024 + kt + cb, &sA[c * 8]);
    }
#pragma unroll
    for (int i = 0; i < 4; i++) {
      int c = i * 256 + tid;
      int r = c >> 3, cb = (c & 7) * 8;
      gl16(B + (size_t)(colBase + r) * 1024 + kt + cb, &sB[c * 8]);
    }
    __syncthreads();
#pragma unroll
    for (int kk = 0; kk < 2; kk++) {
      bv8 af[4];
#pragma unroll
      for (int m = 0; m < 4; m++)
        af[m] = *(const bv8*)&sA[(wr * 64 + m * 16 + l15) * 64 + kk * 32 + l4 * 8];
#pragma unroll
      for (int n = 0; n < 4; n++) {
        bv8 bfr = *(const bv8*)&sB[(wc * 64 + n * 16 + l15) * 64 + kk * 32 + l4 * 8];
        // swapped: D[wcol16][token16]
#pragma unroll
        for (int m = 0; m < 4; m++) acc[m][n] = mfma_bf16(bfr, af[m], acc[m][n]);
      }
    }
    __syncthreads();
  }
  const int b = rowBase >> 10;
  const int tokb = rowBase & 1023;
#pragma unroll
  for (int n = 0; n < 4; n++) {
#pragma unroll
    for (int m = 0; m < 4; m++) {
      int token = tokb + wr * 64 + m * 16 + l15;
#pragma unroll
      for (int e = 0; e < 4; e++) {
        int wcol = colBase + wc * 64 + n * 16 + l4 * 4 + e;
        float val = acc[m][n][e] + bias[wcol];
        VT[(size_t)b * SEQ * DM + (size_t)wcol * SEQ + token] = __float2bfloat16(val);
      }
    }
  }
}

// ---------------- fc_o + mish + residual ----------------
__global__ __launch_bounds__(256) void gemm_o(
    const bf16* __restrict__ A, const bf16* __restrict__ B,
    const float* __restrict__ bias, const float* __restrict__ addsrc,
    float* __restrict__ Cf)
{
  __shared__ __attribute__((aligned(16))) bf16 sA[128 * 64];
  __shared__ __attribute__((aligned(16))) bf16 sB[128 * 64];
  const int tid = threadIdx.x;
  const int lane = tid & 63, wave = tid >> 6;
  const int wr = wave >> 1, wc = wave & 1;
  const int l15 = lane & 15, l4 = lane >> 4;
  const int rowBase = blockIdx.x * 128;
  const int colBase = blockIdx.y * 128;

  fx4 acc[4][4];
#pragma unroll
  for (int m = 0; m < 4; m++)
#pragma unroll
    for (int n = 0; n < 4; n++) acc[m][n] = fx4{0.f, 0.f, 0.f, 0.f};

  for (int kt = 0; kt < 1024; kt += 64) {
#pragma unroll
    for (int i = 0; i < 4; i++) {
      int c = i * 256 + tid;
      int r = c >> 3, cb = (c & 7) * 8;
      gl16(A + (size_t)(rowBase + r) * 1024 + kt + cb, &sA[c * 8]);
    }
#pragma unroll
    for (int i = 0; i < 4; i++) {
      int c = i * 256 + tid;
      int r = c >> 3, cb = (c & 7) * 8;
      gl16(B + (size_t)(colBase + r) * 1024 + kt + cb, &sB[c * 8]);
    }
    __syncthreads();
#pragma unroll
    for (int kk = 0; kk < 2; kk++) {
      bv8 af[4];
#pragma unroll
      for (int m = 0; m < 4; m++)
        af[m] = *(const bv8*)&sA[(wr * 64 + m * 16 + l15) * 64 + kk * 32 + l4 * 8];
#pragma unroll
      for (int n = 0; n < 4; n++) {
        bv8 bfr = *(const bv8*)&sB[(wc * 64 + n * 16 + l15) * 64 + kk * 32 + l4 * 8];
#pragma unroll
        for (int m = 0; m < 4; m++) acc[m][n] = mfma_bf16(af[m], bfr, acc[m][n]);
      }
    }
    __syncthreads();
  }
#pragma unroll
  for (int n = 0; n < 4; n++) {
    int col = colBase + wc * 64 + n * 16 + l15;
    float bvv = bias[col];
#pragma unroll
    for (int m = 0; m < 4; m++) {
      int row0 = rowBase + wr * 64 + m * 16 + l4 * 4;
#pragma unroll
      for (int r = 0; r < 4; r++) {
        size_t idx = (size_t)(row0 + r) * DM + col;
        float val = acc[m][n][r] + bvv;
        float u = __expf(val);
        float num = u * (u + 2.0f);          // (1+u)^2 - 1
        Cf[idx] = addsrc[idx] + val * num / (num + 2.0f);
      }
    }
  }
}

// ---------------- LayerNorm + LIF for q and k in one launch ----------------
__global__ __launch_bounds__(256) void lnlif2_kernel(
    const float* __restrict__ xq, const float* __restrict__ xk,
    const float* __restrict__ gq, const float* __restrict__ beq,
    const float* __restrict__ gk, const float* __restrict__ bek,
    u16* __restrict__ outq, u16* __restrict__ outk)
{
  const int z = blockIdx.y;
  const float* x = z ? xk : xq;
  const float* g = z ? gk : gq;
  const float* be = z ? bek : beq;
  u16* out = z ? outk : outq;
  __shared__ float red[4];
  const int row = blockIdx.x;
  const int tid = threadIdx.x;
  fx4 v = *(const fx4*)&x[(size_t)row * DM + tid * 4];
  float s = v[0] + v[1] + v[2] + v[3];
#pragma unroll
  for (int off = 1; off < 64; off <<= 1) s += __shfl_xor(s, off, 64);
  if ((tid & 63) == 0) red[tid >> 6] = s;
  __syncthreads();
  float mean = (red[0] + red[1] + red[2] + red[3]) * (1.0f / 1024.0f);
  __syncthreads();
  float d0 = v[0] - mean, d1 = v[1] - mean, d2 = v[2] - mean, d3 = v[3] - mean;
  float ss = d0 * d0 + d1 * d1 + d2 * d2 + d3 * d3;
#pragma unroll
  for (int off = 1; off < 64; off <<= 1) ss += __shfl_xor(ss, off, 64);
  if ((tid & 63) == 0) red[tid >> 6] = ss;
  __syncthreads();
  float var = (red[0] + red[1] + red[2] + red[3]) * (1.0f / 1024.0f);
  float rstd = rsqrtf(var + 1e-5f);
  const int c = tid * 4;
  fx4 gg = *(const fx4*)&g[c];
  fx4 bb = *(const fx4*)&be[c];
  float y0 = d0 * rstd * gg[0] + bb[0];
  float y1 = d1 * rstd * gg[1] + bb[1];
  float y2 = d2 * rstd * gg[2] + bb[2];
  float y3 = d3 * rstd * gg[3] + bb[3];
  u32 a = (y0 >= 2.f ? 0x3F80u : 0u) | ((y1 >= 2.f ? 0x3F80u : 0u) << 16);
  u32 b = (y2 >= 2.f ? 0x3F80u : 0u) | ((y3 >= 2.f ? 0x3F80u : 0u) << 16);
  u32* p = (u32*)(out + (size_t)row * DM + c);
  p[0] = a; p[1] = b;
}

// ---------------- fused masked attention, SWAPPED QK^T ----------------
// mfma(K,Q) => lane owns P-row q=l15, k = n*16+l4*4+r (consecutive in r):
// P store = 8 cvt_pk + 4 ds_write_b64; mask = 2 broadcast LDS loads; scalar psum.
__global__ __launch_bounds__(256) void attn_kernel(
    const bf16* __restrict__ qb, const bf16* __restrict__ kb, const bf16* __restrict__ vt,
    const u32* __restrict__ mwT, float* __restrict__ of, bf16* __restrict__ ob)
{
  __shared__ __attribute__((aligned(16))) bf16 sK[2][64 * 64];
  __shared__ __attribute__((aligned(16))) bf16 sV[2][64 * 64];
  __shared__ __attribute__((aligned(16))) bf16 sP[4][16 * 64];
  __shared__ __attribute__((aligned(16))) u32 sM[2][128];
  const int qt = blockIdx.x, h = blockIdx.y, b = blockIdx.z;
  const int tid = threadIdx.x, lane = tid & 63, wave = tid >> 6;
  const int l15 = lane & 15, l4 = lane >> 4;
  const size_t qrow0 = (size_t)b * SEQ + qt * 64;
  const bf16* kB = kb + (size_t)b * SEQ * DM + h * 64;
  const bf16* vB = vt + (size_t)b * SEQ * DM + (size_t)(h * 64) * SEQ;
  const u32*  mB = mwT + (size_t)b * 32768 + qt * 64;

  auto STAGE = [&](int t, int buf) {
    const int kvb = t * 64;
#pragma unroll
    for (int i = 0; i < 2; i++) {
      int c = i * 256 + tid;
      int row = c >> 3;
      int sb = ((c & 7) * 16) ^ ((row & 7) << 4);
      gl16(kB + (size_t)(kvb + row) * DM + (sb >> 1), &sK[buf][c * 8]);
      gl16(vB + (size_t)row * SEQ + kvb + (sb >> 1), &sV[buf][c * 8]);
    }
    if (tid < 32) {
      int w = tid >> 4, rg = (tid & 15) * 4;
      uint4 mv = *(const uint4*)&mB[(size_t)(t * 2 + w) * 1024 + rg];
      *(uint4*)&sM[buf][w * 64 + rg] = mv;
    }
  };

  // Q fragment (B-operand): rows wave*16+l15
  bv8 qf[2];
#pragma unroll
  for (int kk = 0; kk < 2; kk++)
    qf[kk] = *(const bv8*)&qb[(qrow0 + wave * 16 + l15) * DM + h * 64 + kk * 32 + l4 * 8];

  fx4 acc_o[4];
#pragma unroll
  for (int n = 0; n < 4; n++) acc_o[n] = fx4{0.f, 0.f, 0.f, 0.f};
  float psum = 0.f;

  char* sPw = (char*)sP[wave];
  const int swzq = (l15 & 7) << 4;
  STAGE(0, 0);

  for (int t = 0; t < 16; t++) {
    const int cur = t & 1;
    asm volatile("s_waitcnt vmcnt(0) lgkmcnt(0)" ::: "memory");
    __builtin_amdgcn_s_barrier();
    if (t < 15) STAGE(t + 1, cur ^ 1);

    const char* sKc = (const char*)sK[cur];
    const char* sVc = (const char*)sV[cur];

    // QK^T swapped: accs[n] = S^T fragment (row = k-local, col = q = l15)
    fx4 accs[4];
#pragma unroll
    for (int n = 0; n < 4; n++) accs[n] = fx4{0.f, 0.f, 0.f, 0.f};
    __builtin_amdgcn_s_setprio(1);
#pragma unroll
    for (int kk = 0; kk < 2; kk++) {
#pragma unroll
      for (int n = 0; n < 4; n++) {
        int row = n * 16 + l15;
        bv8 kf = *(const bv8*)(sKc + row * 128 + ((kk * 64 + l4 * 16) ^ ((row & 7) << 4)));
        accs[n] = mfma_bf16(kf, qf[kk], accs[n]);
      }
    }
    __builtin_amdgcn_s_setprio(0);

    // mask: row q=l15, words for k in [t*64, t*64+64)
    u32 m0 = sM[cur][wave * 16 + l15];
    u32 m1 = sM[cur][64 + wave * 16 + l15];
    u32 tb[4] = {m0 >> (l4 * 4), m0 >> (16 + l4 * 4), m1 >> (l4 * 4), m1 >> (16 + l4 * 4)};

#pragma unroll
    for (int n = 0; n < 4; n++) {
      float p0, p1, p2, p3;
      {
        float e0 = exp2f(accs[n][0] * 0.18033688011112042f);
        float e1 = exp2f(accs[n][1] * 0.18033688011112042f);
        float e2 = exp2f(accs[n][2] * 0.18033688011112042f);
        float e3 = exp2f(accs[n][3] * 0.18033688011112042f);
        p0 = (tb[n] & 1u) ? e0 : 1.0f;
        p1 = ((tb[n] >> 1) & 1u) ? e1 : 1.0f;
        p2 = ((tb[n] >> 2) & 1u) ? e2 : 1.0f;
        p3 = ((tb[n] >> 3) & 1u) ? e3 : 1.0f;
      }
      psum += (p0 + p1) + (p2 + p3);
      uint2 pk;
      pk.x = cvt_pk_bf16(p0, p1);
      pk.y = cvt_pk_bf16(p2, p3);
      *(uint2*)(sPw + l15 * 128 + ((n * 32 + l4 * 8) ^ swzq)) = pk;
    }

    // PV (sP wave-private; in-order DS pipe)
    __builtin_amdgcn_s_setprio(1);
#pragma unroll
    for (int kk = 0; kk < 2; kk++) {
      bv8 pa = *(const bv8*)(sPw + l15 * 128 + ((kk * 64 + l4 * 16) ^ swzq));
#pragma unroll
      for (int n = 0; n < 4; n++) {
        int row = n * 16 + l15;
        bv8 vf = *(const bv8*)(sVc + row * 128 + ((kk * 64 + l4 * 16) ^ ((row & 7) << 4)));
        acc_o[n] = mfma_bf16(pa, vf, acc_o[n]);
      }
    }
    __builtin_amdgcn_s_setprio(0);
  }

  // denom for q=l15 lives on 4 lanes; combine then redistribute to acc_o's q=l4*4+r
  psum += __shfl_xor(psum, 16, 64);
  psum += __shfl_xor(psum, 32, 64);
#pragma unroll
  for (int r = 0; r < 4; r++) {
    float inv = 1.0f / __shfl(psum, l4 * 4 + r, 64);
    size_t row = qrow0 + wave * 16 + (l4 << 2) + r;
#pragma unroll
    for (int n = 0; n < 4; n++) {
      size_t idx = row * DM + h * 64 + n * 16 + l15;
      float val = acc_o[n][r] * inv;
      of[idx] = val;
      ob[idx] = __float2bfloat16(val);
    }
  }
}

extern "C" void kernel_launch(void* const* d_in, const int* in_sizes, int n_in,
                              void* d_out, int out_size, void* d_ws, size_t ws_size,
                              hipStream_t stream) {
  (void)in_sizes; (void)n_in; (void)out_size; (void)ws_size;
  const float* Q    = (const float*)d_in[0];
  const float* Kin  = (const float*)d_in[1];
  const float* mask = (const float*)d_in[2];
  const float* Wq   = (const float*)d_in[3];
  const float* bq   = (const float*)d_in[4];
  const float* Wk   = (const float*)d_in[5];
  const float* bk   = (const float*)d_in[6];
  const float* Wv   = (const float*)d_in[7];
  const float* bv   = (const float*)d_in[8];
  const float* Wo   = (const float*)d_in[9];
  const float* bo   = (const float*)d_in[10];
  const float* g_q  = (const float*)d_in[11];
  const float* be_q = (const float*)d_in[12];
  const float* g_k  = (const float*)d_in[13];
  const float* be_k = (const float*)d_in[14];
  float* out = (float*)d_out;

  char* w = (char*)d_ws;
  size_t off = 0;
  auto alloc = [&](size_t bytes) -> char* {
    char* p = w + off;
    off += (bytes + 255) & ~(size_t)255;
    return p;
  };
  bf16* q_spike = (bf16*)alloc(SZ * 2);
  bf16* k_spike = (bf16*)alloc(SZ * 2);
  float* xq     = (float*)alloc(SZ * 4);
  float* xk     = (float*)alloc(SZ * 4);
  bf16* vtb     = (bf16*)alloc(SZ * 2);
  u32* mwords   = (u32*)alloc(SZ / 32 * 4);
  bf16* wqe = (bf16*)alloc((size_t)DM * DM * 3 * 2);
  bf16* wke = (bf16*)alloc((size_t)DM * DM * 3 * 2);
  bf16* wvb = (bf16*)alloc((size_t)DM * DM * 2);
  bf16* wob = (bf16*)alloc((size_t)DM * DM * 2);
  // aliases (lifetimes disjoint):
  bf16* qbn = q_spike;          // q_spike dead after gemm_qk
  bf16* kbn = k_spike;          // k_spike dead after gemm_vT
  float* attn_out = xq;         // xq dead after lnlif2
  bf16* attn_outb = (bf16*)xk;  // xk dead after lnlif2

  prep_weights<<<dim3(DM * DM / 1024, 4), 256, 0, stream>>>(Wq, Wk, Wv, Wo, wqe, wke, wvb, wob);
  spike2_kernel<<<dim3(SZ / 1024, 2), 256, 0, stream>>>(Q, Kin, (u16*)q_spike, (u16*)k_spike);
  maskpack_kernel<<<SZ / 256, 256, 0, stream>>>(mask, mwords);

  gemm_qk<<<dim3(64, 8, 2), 256, 0, stream>>>(q_spike, k_spike, wqe, wke, bq, bk, xq, xk);
  gemm_vT<<<dim3(64, 8), 256, 0, stream>>>(k_spike, wvb, bv, vtb);

  lnlif2_kernel<<<dim3(MROWS, 2), 256, 0, stream>>>(xq, xk, g_q, be_q, g_k, be_k,
                                                    (u16*)qbn, (u16*)kbn);

  attn_kernel<<<dim3(16, NH, NBATCH), 256, 0, stream>>>(qbn, kbn, vtb, mwords, attn_out, attn_outb);

  gemm_o<<<dim3(64, 8), 256, 0, stream>>>(attn_outb, wob, bo, attn_out, out);
}